// Round 9
// baseline (525.093 us; speedup 1.0000x reference)
//
#include <hip/hip_runtime.h>
#include <hip/hip_bf16.h>

#define V 3
#define N 4096
#define D 512
#define H 128
#define C 5
#define KS 2                    // split-K factor for k2
#define LOG2E 1.4426950408889634f

typedef short short8 __attribute__((ext_vector_type(8)));
typedef float floatx4 __attribute__((ext_vector_type(4)));
typedef int   intx4  __attribute__((ext_vector_type(4)));

__device__ __forceinline__ unsigned short f2bf(float f){
  __hip_bfloat16 h = __float2bfloat16(f);
  return *reinterpret_cast<unsigned short*>(&h);
}
// RNE pack of two non-NaN floats to packed bf16x2
__device__ __forceinline__ unsigned int pk_bf16(float a, float b){
  unsigned int ua = __float_as_uint(a), ub = __float_as_uint(b);
  ua += 0x7FFFu + ((ua >> 16) & 1u);
  ub += 0x7FFFu + ((ub >> 16) & 1u);
  return (ua >> 16) | (ub & 0xFFFF0000u);
}

// ---------------- K1: h = data@gac_w (-> hT bf16 [V][H][N]), mlp = data@mlp_w,
// ----------------     e1/e2 = (h.a1, h.a2) * log2e  (K1b folded in) ----------------
#define TN1 16
__global__ __launch_bounds__(256) void k1_gemm(
    const float* __restrict__ data,
    const float* __restrict__ gac_w,
    const float* __restrict__ mlp_w,
    const float* __restrict__ a1, const float* __restrict__ a2,
    unsigned short* __restrict__ hT, float* __restrict__ mlp_out,
    float* __restrict__ e1, float* __restrict__ e2)
{
  const int v = blockIdx.y;
  const int n0 = blockIdx.x * TN1;
  const int t = threadIdx.x;
  const int half = t >> 7, tt = t & 127;   // half 0: d 0..255, half 1: d 256..511
  __shared__ float ds[D][20];              // transposed data tile; 40 KB
  __shared__ float epart[2][2][TN1];       // e1/e2 wave partials
  float* comb = &ds[0][0];                 // aliased post-compute: [2][TN1][H]
  const float* dp = data + ((size_t)v*N + n0)*D;
  for (int j = t; j < TN1*D; j += 256){
    int r = j >> 9, d = j & (D-1);
    ds[d][r] = dp[(size_t)r*D + d];
  }
  __syncthreads();
  float ag[TN1], am[TN1];
  #pragma unroll
  for (int r=0;r<TN1;r++){ ag[r]=0.f; am[r]=0.f; }
  const int d0 = half*256;
  const float* gw = gac_w + (size_t)v*D*H + tt;
  const float* mw = mlp_w + (size_t)v*D*H + tt;
  for (int d=d0; d<d0+256; d++){
    float wg = gw[(size_t)d*H];
    float wm = mw[(size_t)d*H];
    const float4* p = (const float4*)&ds[d][0];
    float4 x0=p[0], x1=p[1], x2=p[2], x3=p[3];
    float xv[16] = {x0.x,x0.y,x0.z,x0.w, x1.x,x1.y,x1.z,x1.w,
                    x2.x,x2.y,x2.z,x2.w, x3.x,x3.y,x3.z,x3.w};
    #pragma unroll
    for (int r=0;r<TN1;r++){
      ag[r] = fmaf(xv[r], wg, ag[r]);
      am[r] = fmaf(xv[r], wm, am[r]);
    }
  }
  __syncthreads();                         // all ds reads done; safe to alias comb
  if (half == 1){
    #pragma unroll
    for (int r=0;r<TN1;r++){
      comb[r*H + tt]          = ag[r];
      comb[TN1*H + r*H + tt]  = am[r];
    }
  }
  __syncthreads();
  if (half == 0){
    float* mp = mlp_out + ((size_t)v*N + n0)*H + tt;
    unsigned short pk[TN1];
    const float a1v = a1[v*H + tt], a2v = a2[v*H + tt];
    #pragma unroll
    for (int r=0;r<TN1;r++){
      ag[r] += comb[r*H + tt];
      am[r] += comb[TN1*H + r*H + tt];
      mp[(size_t)r*H] = am[r];
      pk[r] = f2bf(ag[r]);
    }
    uint4* hp = (uint4*)(hT + ((size_t)v*H + tt)*N + n0);   // transposed bf16 h
    hp[0] = *(uint4*)&pk[0];
    hp[1] = *(uint4*)&pk[8];
    // e1/e2: reduce ag[r]*a1/a2 across the 128 half-0 threads (waves 0,1)
    #pragma unroll
    for (int r=0;r<TN1;r++){
      float s1 = ag[r]*a1v, s2 = ag[r]*a2v;
      #pragma unroll
      for (int o=32;o>0;o>>=1){ s1 += __shfl_down(s1,o); s2 += __shfl_down(s2,o); }
      if ((tt&63)==0){ epart[0][tt>>6][r]=s1; epart[1][tt>>6][r]=s2; }
    }
  }
  __syncthreads();
  if (t < TN1)        e1[(size_t)v*N + n0 + t]       = LOG2E*(epart[0][0][t]    + epart[0][1][t]);
  else if (t < 2*TN1) e2[(size_t)v*N + n0 + (t-TN1)] = LOG2E*(epart[1][0][t-TN1]+ epart[1][1][t-TN1]);
}

// ---------------- K2: masked graph attention via bf16 MFMA, split-K partials ----------------
// Grid (N/16, KS, V), 512 thr. Each block: 16 rows x 128 cols x 2048 K.
// Producer: thread t owns fragment-lane (kstep8 = t>>6, flane = t&63): computes
// 8 exps and ONE 16B short8 store (lane-stride-16 -> conflict-free LDS).
// Consumer: wave w owns 16 cols, 8 MFMAs per 256-K chunk. Ping-pong + reg prefetch.
// No max-subtraction (logits O(+-9) log2e-scaled; masked weights exactly 0).
#define KC2 256
__global__ __launch_bounds__(512, 8) void k2_attn(
    const unsigned short* __restrict__ hT, const int* __restrict__ adj,
    const float* __restrict__ e1g, const float* __restrict__ e2g,   // pre-scaled by log2e
    float* __restrict__ pacc, float* __restrict__ pdenG)
{
  const int v = blockIdx.z;
  const int ksid = blockIdx.y;
  const int n0 = blockIdx.x * 16;
  const int kbase = ksid * (N/KS);
  const int t = threadIdx.x;
  const int w = t >> 6, flane = t & 63;
  const int row = flane & 15, quad = flane >> 4;
  __shared__ __align__(16) unsigned short Afrag[2][8][64][8];   // 16 KB ping-pong
  __shared__ float pden_l[8][16];

  // producer pointers: this thread's 8-k strip, advancing 256 per chunk
  const intx4* ap4 = (const intx4*)(adj + ((size_t)v*N + n0 + row)*N
                                    + kbase + w*32 + quad*8);
  const float4* ep4 = (const float4*)(e2g + (size_t)v*N + kbase + w*32 + quad*8);
  const float e1r = e1g[(size_t)v*N + n0 + row];
  float psum = 0.f;

  // consumer: wave w owns cols w*16 .. w*16+15
  const int col = w*16 + row;
  const unsigned short* bcol = hT + ((size_t)v*H + col)*N + kbase + quad*8;
  floatx4 acc = {0.f, 0.f, 0.f, 0.f};

  intx4  av0 = __builtin_nontemporal_load(ap4);
  intx4  av1 = __builtin_nontemporal_load(ap4 + 1);
  float4 ev0 = ep4[0];
  float4 ev1 = ep4[1];

  const int NCH = (N/KS)/KC2;                 // 8 chunks
  #pragma unroll 1
  for (int c = 0; c < NCH; c++){
    // produce chunk c into buffer c&1 (from prefetched regs)
    {
      float ev[8] = {ev0.x,ev0.y,ev0.z,ev0.w, ev1.x,ev1.y,ev1.z,ev1.w};
      int   aa[8] = {av0.x,av0.y,av0.z,av0.w, av1.x,av1.y,av1.z,av1.w};
      float wv[8];
      #pragma unroll
      for (int j=0;j<8;j++){
        float y = e1r + ev[j];
        y = fmaxf(y, 0.25f*y);               // leaky (scale-invariant) BEFORE mask
        float e = exp2f(y);
        wv[j] = (aa[j] > 0) ? e : 0.f;       // masked weight exactly 0
        psum += wv[j];
      }
      union { short8 s; unsigned int u[4]; } a8;
      #pragma unroll
      for (int j=0;j<4;j++) a8.u[j] = pk_bf16(wv[2*j], wv[2*j+1]);
      *(short8*)&Afrag[c&1][w][flane][0] = a8.s;
    }
    // prefetch chunk c+1
    if (c+1 < NCH){
      av0 = __builtin_nontemporal_load(ap4 + (c+1)*64);
      av1 = __builtin_nontemporal_load(ap4 + (c+1)*64 + 1);
      ev0 = ep4[(c+1)*64];
      ev1 = ep4[(c+1)*64 + 1];
    }
    __syncthreads();
    // consume chunk c
    const int m0 = c * KC2;
    #pragma unroll
    for (int ks=0; ks<8; ks++){
      short8 a8 = *(const short8*)&Afrag[c&1][ks][flane][0];
      short8 b8 = *(const short8*)(bcol + m0 + ks*32);
      acc = __builtin_amdgcn_mfma_f32_16x16x32_bf16(a8, b8, acc, 0, 0, 0);
    }
    __syncthreads();
  }
  // wave-local row denominators (lanes {row, row+16, row+32, row+48})
  psum += __shfl_down(psum, 32);
  psum += __shfl_down(psum, 16);
  if (flane < 16) pden_l[w][flane] = psum;
  __syncthreads();
  // write partials
  const size_t pb = (((size_t)v*KS + ksid)*(N/16) + blockIdx.x);
  float* pa = pacc + pb*(16*H);
  #pragma unroll
  for (int reg=0; reg<4; reg++){
    const int r = quad*4 + reg;
    pa[r*H + col] = acc[reg];
  }
  if (t < 16){
    float den = 0.f;
    #pragma unroll
    for (int k=0;k<8;k++) den += pden_l[k][t];
    pdenG[pb*16 + t] = den;
  }
}

// ---------------- K2r: combine split-K partials + epilogue ----------------
__global__ __launch_bounds__(256) void k2_reduce(
    const float* __restrict__ pacc, const float* __restrict__ pdenG,
    const float* __restrict__ mlp_out,
    const float* __restrict__ gac_b, const float* __restrict__ mlp_b,
    float* __restrict__ feat)
{
  const int v = blockIdx.y;
  const int n0 = blockIdx.x * 16;
  const int t = threadIdx.x;
  const int col = t & 127, rh = t >> 7;
  const size_t pb0 = (((size_t)v*KS + 0)*(N/16) + blockIdx.x);
  const size_t pb1 = (((size_t)v*KS + 1)*(N/16) + blockIdx.x);
  const float* pa0 = pacc + pb0*(16*H);
  const float* pa1 = pacc + pb1*(16*H);
  const float gb = gac_b[v*H + col];
  const float mb = mlp_b[v*H + col];
  #pragma unroll
  for (int i=0;i<8;i++){
    const int r = rh*8 + i;
    float num = pa0[r*H + col] + pa1[r*H + col];
    float den = pdenG[pb0*16 + r] + pdenG[pb1*16 + r];
    float x = num/den + gb;
    x = (x >= 0.f) ? x : 0.25f*x;
    const size_t idx = ((size_t)v*N + n0 + r)*H + col;
    feat[idx] = x + mlp_out[idx] + mb;
  }
}

// ---------------- K3: per-node HxH outer-product attention + fc + conf gate ----------------
#define TN3 8
__global__ __launch_bounds__(128) void k3_sgfe(
    const float* __restrict__ feat,
    const float* __restrict__ qw, const float* __restrict__ qb,
    const float* __restrict__ kw, const float* __restrict__ kb,
    const float* __restrict__ vw, const float* __restrict__ vb,
    const float* __restrict__ fcw, const float* __restrict__ fcb,
    const float* __restrict__ confw, const float* __restrict__ confb,
    float* __restrict__ feat2)
{
  const int v = blockIdx.y;
  const int n0 = blockIdx.x * TN3;
  const int t = threadIdx.x;
  const int W = t >> 6, lane = t & 63;
  __shared__ float fsT[H][12];             // feat tile transposed, padded
  __shared__ float Qs[TN3][H];
  __shared__ float2 KVs[TN3][H];
  __shared__ float As2T[H][12];            // agg, [dim][node], padded
  __shared__ float rbuf2[TN3][2];
  const float* fp = feat + ((size_t)v*N + n0)*H + t;
  #pragma unroll
  for (int r=0;r<TN3;r++) fsT[t][r] = fp[(size_t)r*H];
  __syncthreads();
  const float* qwp = qw + (size_t)v*H*H + t;
  const float* kwp = kw + (size_t)v*H*H + t;
  const float* vwp = vw + (size_t)v*H*H + t;
  float Qr[TN3], Kr[TN3], Vr[TN3];
  {
    const float qbv = qb[v*H+t], kbv = kb[v*H+t], vbv = vb[v*H+t];
    #pragma unroll
    for (int r=0;r<TN3;r++){ Qr[r]=qbv; Kr[r]=kbv; Vr[r]=vbv; }
  }
  for (int i=0;i<H;i++){   // one weight sweep computes Q,K,V for all 8 nodes
    float wq = qwp[(size_t)i*H];
    float wk = kwp[(size_t)i*H];
    float wv = vwp[(size_t)i*H];
    float4 f0 = *(const float4*)&fsT[i][0];
    float4 f1 = *(const float4*)&fsT[i][4];
    float fv[8] = {f0.x,f0.y,f0.z,f0.w, f1.x,f1.y,f1.z,f1.w};
    #pragma unroll
    for (int r=0;r<TN3;r++){
      Qr[r] = fmaf(fv[r], wq, Qr[r]);
      Kr[r] = fmaf(fv[r], wk, Kr[r]);
      Vr[r] = fmaf(fv[r], wv, Vr[r]);
    }
  }
  #pragma unroll
  for (int r=0;r<TN3;r++){
    Qs[r][t] = Qr[r];
    KVs[r][t] = make_float2(Kr[r], Vr[r]);
  }
  __syncthreads();
  // attention: wave W handles nodes r = 2*p + W; each lane covers dims lane, lane+64
  const float invs = 0.08838834764831845f;  // 1/sqrt(128)
  #pragma unroll
  for (int p=0;p<4;p++){
    const int r = 2*p + W;
    const float qa = Qs[r][lane]   * invs;
    const float qb2 = Qs[r][lane+64] * invs;
    float sA=0.f, aA=0.f, sB=0.f, aB=0.f;
    const float4* kvp = (const float4*)&KVs[r][0];
    #pragma unroll 4
    for (int oo=0; oo<H/2; oo++){
      float4 kv2 = kvp[oo];                // two (K,V) pairs per b128
      float eA0 = __expf(qa*kv2.x);  sA += eA0; aA = fmaf(eA0, kv2.y, aA);
      float eA1 = __expf(qa*kv2.z);  sA += eA1; aA = fmaf(eA1, kv2.w, aA);
      float eB0 = __expf(qb2*kv2.x); sB += eB0; aB = fmaf(eB0, kv2.y, aB);
      float eB1 = __expf(qb2*kv2.z); sB += eB1; aB = fmaf(eB1, kv2.w, aB);
    }
    As2T[lane][r]    = aA/sA;
    As2T[lane+64][r] = aB/sB;
  }
  __syncthreads();
  // fc: g[r] = sum_i As2T[i][r] * fcw[i][t]  (fcw read ONCE per block)
  const float* fcwp = fcw + (size_t)v*H*H + t;
  const float fcbv = fcb[v*H+t];
  float g[TN3];
  #pragma unroll
  for (int r=0;r<TN3;r++) g[r] = fcbv;
  for (int i=0;i<H;i++){
    float fw = fcwp[(size_t)i*H];
    float4 a0 = *(const float4*)&As2T[i][0];
    float4 a1v = *(const float4*)&As2T[i][4];
    g[0] = fmaf(a0.x, fw, g[0]);  g[1] = fmaf(a0.y, fw, g[1]);
    g[2] = fmaf(a0.z, fw, g[2]);  g[3] = fmaf(a0.w, fw, g[3]);
    g[4] = fmaf(a1v.x, fw, g[4]); g[5] = fmaf(a1v.y, fw, g[5]);
    g[6] = fmaf(a1v.z, fw, g[6]); g[7] = fmaf(a1v.w, fw, g[7]);
  }
  const float cwv = confw[v*H+t];
  const float cbv = confb[v];
  #pragma unroll
  for (int r=0;r<TN3;r++){
    g[r] = fmaxf(g[r], 0.f);
    float psm = g[r]*cwv;
    #pragma unroll
    for (int o=32;o>0;o>>=1) psm += __shfl_down(psm,o);
    if (lane==0) rbuf2[r][W] = psm;
  }
  __syncthreads();
  #pragma unroll
  for (int r=0;r<TN3;r++){
    const float conf = rbuf2[r][0] + rbuf2[r][1] + cbv;
    feat2[((size_t)v*N + n0 + r)*H + t] = g[r]*conf;
  }
}

// ---------------- K4: final classifier [N, V*H] @ [V*H, C] ----------------
__global__ __launch_bounds__(64) void k4_cls(
    const float* __restrict__ feat2,
    const float* __restrict__ mm_w, const float* __restrict__ mm_b,
    float* __restrict__ out)
{
  const int n = blockIdx.x, t = threadIdx.x;
  float a[C] = {0,0,0,0,0};
  for (int j=t; j<V*H; j+=64){
    int vv = j >> 7, hh = j & (H-1);
    float f = feat2[((size_t)vv*N + n)*H + hh];
    #pragma unroll
    for (int c=0;c<C;c++) a[c] = fmaf(f, mm_w[j*C+c], a[c]);
  }
  #pragma unroll
  for (int c=0;c<C;c++){
    #pragma unroll
    for (int o=32;o>0;o>>=1) a[c] += __shfl_down(a[c],o);
  }
  if (t==0){
    #pragma unroll
    for (int c=0;c<C;c++) out[(size_t)n*C+c] = a[c] + mm_b[c];
  }
}

extern "C" void kernel_launch(void* const* d_in, const int* in_sizes, int n_in,
                              void* d_out, int out_size, void* d_ws, size_t ws_size,
                              hipStream_t stream)
{
  (void)in_sizes; (void)n_in; (void)out_size; (void)ws_size;
  const float* data  = (const float*)d_in[0];
  const int*   adj   = (const int*)d_in[1];
  const float* gac_w = (const float*)d_in[2];
  const float* gac_b = (const float*)d_in[3];
  const float* a1    = (const float*)d_in[4];
  const float* a2    = (const float*)d_in[5];
  const float* mlp_w = (const float*)d_in[6];
  const float* mlp_b = (const float*)d_in[7];
  const float* q_w   = (const float*)d_in[8];
  const float* q_b   = (const float*)d_in[9];
  const float* k_w   = (const float*)d_in[10];
  const float* k_b   = (const float*)d_in[11];
  const float* v_w   = (const float*)d_in[12];
  const float* v_b   = (const float*)d_in[13];
  const float* fc_w  = (const float*)d_in[14];
  const float* fc_b  = (const float*)d_in[15];
  const float* cw    = (const float*)d_in[16];
  const float* cb    = (const float*)d_in[17];
  const float* mm_w  = (const float*)d_in[18];
  const float* mm_b  = (const float*)d_in[19];

  float* ws = (float*)d_ws;
  const size_t VNH = (size_t)V*N*H;
  float* mlp   = ws;
  float* feat  = ws + VNH;
  float* feat2 = ws + 2*VNH;
  float* e1    = ws + 3*VNH;
  float* e2    = e1 + (size_t)V*N;
  unsigned short* hT = (unsigned short*)(e2 + (size_t)V*N);  // [V][H][N] bf16
  float* pacc  = (float*)(hT + VNH);                         // [V][KS][N/16][16][H]
  float* pden  = pacc + (size_t)V*KS*(N/16)*16*H;            // [V][KS][N/16][16]

  k1_gemm<<<dim3(N/TN1, V), 256, 0, stream>>>(data, gac_w, mlp_w, a1, a2,
                                              hT, mlp, e1, e2);
  k2_attn<<<dim3(N/16, KS, V), 512, 0, stream>>>(hT, adj, e1, e2, pacc, pden);
  k2_reduce<<<dim3(N/16, V), 256, 0, stream>>>(pacc, pden, mlp, gac_b, mlp_b, feat);
  k3_sgfe<<<dim3(N/TN3, V), 128, 0, stream>>>(feat, q_w, q_b, k_w, k_b, v_w, v_b,
                                              fc_w, fc_b, cw, cb, feat2);
  k4_cls<<<dim3(N),          64, 0, stream>>>(feat2, mm_w, mm_b, (float*)d_out);
}

// Round 10
// 475.274 us; speedup vs baseline: 1.1048x; 1.1048x over previous
//
#include <hip/hip_runtime.h>
#include <hip/hip_bf16.h>

#define V 3
#define N 4096
#define D 512
#define H 128
#define C 5
#define KS 4                    // split-K factor for k2
#define M2 64                   // rows per k2 block
#define LOG2E 1.4426950408889634f

typedef short short8 __attribute__((ext_vector_type(8)));
typedef float floatx4 __attribute__((ext_vector_type(4)));
typedef int   intx4  __attribute__((ext_vector_type(4)));

__device__ __forceinline__ unsigned short f2bf(float f){
  __hip_bfloat16 h = __float2bfloat16(f);
  return *reinterpret_cast<unsigned short*>(&h);
}
// RNE pack of two non-NaN floats to packed bf16x2
__device__ __forceinline__ unsigned int pk_bf16(float a, float b){
  unsigned int ua = __float_as_uint(a), ub = __float_as_uint(b);
  ua += 0x7FFFu + ((ua >> 16) & 1u);
  ub += 0x7FFFu + ((ub >> 16) & 1u);
  return (ua >> 16) | (ub & 0xFFFF0000u);
}

// ---------------- K1: h = data@gac_w (-> hT bf16 [V][H][N]), mlp = data@mlp_w,
// ----------------     e1/e2 = (h.a1, h.a2) * log2e  (K1b folded in) ----------------
#define TN1 16
__global__ __launch_bounds__(256) void k1_gemm(
    const float* __restrict__ data,
    const float* __restrict__ gac_w,
    const float* __restrict__ mlp_w,
    const float* __restrict__ a1, const float* __restrict__ a2,
    unsigned short* __restrict__ hT, float* __restrict__ mlp_out,
    float* __restrict__ e1, float* __restrict__ e2)
{
  const int v = blockIdx.y;
  const int n0 = blockIdx.x * TN1;
  const int t = threadIdx.x;
  const int half = t >> 7, tt = t & 127;   // half 0: d 0..255, half 1: d 256..511
  __shared__ float ds[D][20];              // transposed data tile; 40 KB
  __shared__ float epart[2][2][TN1];       // e1/e2 wave partials
  float* comb = &ds[0][0];                 // aliased post-compute: [2][TN1][H]
  const float* dp = data + ((size_t)v*N + n0)*D;
  for (int j = t; j < TN1*D; j += 256){
    int r = j >> 9, d = j & (D-1);
    ds[d][r] = dp[(size_t)r*D + d];
  }
  __syncthreads();
  float ag[TN1], am[TN1];
  #pragma unroll
  for (int r=0;r<TN1;r++){ ag[r]=0.f; am[r]=0.f; }
  const int d0 = half*256;
  const float* gw = gac_w + (size_t)v*D*H + tt;
  const float* mw = mlp_w + (size_t)v*D*H + tt;
  for (int d=d0; d<d0+256; d++){
    float wg = gw[(size_t)d*H];
    float wm = mw[(size_t)d*H];
    const float4* p = (const float4*)&ds[d][0];
    float4 x0=p[0], x1=p[1], x2=p[2], x3=p[3];
    float xv[16] = {x0.x,x0.y,x0.z,x0.w, x1.x,x1.y,x1.z,x1.w,
                    x2.x,x2.y,x2.z,x2.w, x3.x,x3.y,x3.z,x3.w};
    #pragma unroll
    for (int r=0;r<TN1;r++){
      ag[r] = fmaf(xv[r], wg, ag[r]);
      am[r] = fmaf(xv[r], wm, am[r]);
    }
  }
  __syncthreads();                         // all ds reads done; safe to alias comb
  if (half == 1){
    #pragma unroll
    for (int r=0;r<TN1;r++){
      comb[r*H + tt]          = ag[r];
      comb[TN1*H + r*H + tt]  = am[r];
    }
  }
  __syncthreads();
  if (half == 0){
    float* mp = mlp_out + ((size_t)v*N + n0)*H + tt;
    unsigned short pk[TN1];
    const float a1v = a1[v*H + tt], a2v = a2[v*H + tt];
    #pragma unroll
    for (int r=0;r<TN1;r++){
      ag[r] += comb[r*H + tt];
      am[r] += comb[TN1*H + r*H + tt];
      mp[(size_t)r*H] = am[r];
      pk[r] = f2bf(ag[r]);
    }
    uint4* hp = (uint4*)(hT + ((size_t)v*H + tt)*N + n0);   // transposed bf16 h
    hp[0] = *(uint4*)&pk[0];
    hp[1] = *(uint4*)&pk[8];
    // e1/e2: reduce ag[r]*a1/a2 across the 128 half-0 threads (waves 0,1)
    #pragma unroll
    for (int r=0;r<TN1;r++){
      float s1 = ag[r]*a1v, s2 = ag[r]*a2v;
      #pragma unroll
      for (int o=32;o>0;o>>=1){ s1 += __shfl_down(s1,o); s2 += __shfl_down(s2,o); }
      if ((tt&63)==0){ epart[0][tt>>6][r]=s1; epart[1][tt>>6][r]=s2; }
    }
  }
  __syncthreads();
  if (t < TN1)        e1[(size_t)v*N + n0 + t]       = LOG2E*(epart[0][0][t]    + epart[0][1][t]);
  else if (t < 2*TN1) e2[(size_t)v*N + n0 + (t-TN1)] = LOG2E*(epart[1][0][t-TN1]+ epart[1][1][t-TN1]);
}

// ---------------- K2: masked graph attention via bf16 MFMA ----------------
// 64 rows x 128 cols per block, split-K=4 (K-slice 1024, 8 chunks of 128).
// B-fragment (global, L2/L3) reused across 4 row-tiles -> 4x less B traffic
// than 16-row blocks (768->192 MB). Producer: thread t fills fragment-lane l
// of tiles (rt=w>>2, ks=w&3) and (rt+2, ks) -- contiguous 16B LDS stores
// (r9-verified conflict-free). No max-subtraction (logits O(+-9) log2e-scaled;
// masked weights exactly 0, matching ref exp(NEG-max)==0).
__global__ __launch_bounds__(512, 4) void k2_attn(
    const unsigned short* __restrict__ hT, const int* __restrict__ adj,
    const float* __restrict__ e1g, const float* __restrict__ e2g,   // pre-scaled by log2e
    float* __restrict__ pacc, float* __restrict__ pdenG)
{
  const int v = blockIdx.z;
  const int ksid = blockIdx.y;
  const int n0 = blockIdx.x * M2;
  const int kbase = ksid * (N/KS);            // 1024-wide K slice
  const int t = threadIdx.x;
  const int w = t >> 6, l = t & 63;
  __shared__ __align__(16) unsigned short Afrag[2][4][4][64][8]; // [buf][rt][ks][lane][j] 32KB
  __shared__ float pden_sh[M2][4];            // [row][ks-slot]

  // ---- producer setup ----
  const int ksl  = w & 3;                     // ks tile this thread feeds
  const int quad = l >> 4;
  const int rt0  = w >> 2;                    // 0..1
  const int row0 = rt0*16 + (l & 15);         // 0..31
  const int row1 = row0 + 32;                 // 32..63 (tile rt0+2)
  const int koff = ksl*32 + quad*8;           // k offset inside a 128-chunk
  const intx4* ap0 = (const intx4*)(adj + ((size_t)v*N + n0 + row0)*N + kbase + koff);
  const intx4* ap1 = (const intx4*)(adj + ((size_t)v*N + n0 + row1)*N + kbase + koff);
  const float4* ep = (const float4*)(e2g + (size_t)v*N + kbase + koff);
  const float e1r0 = e1g[(size_t)v*N + n0 + row0];
  const float e1r1 = e1g[(size_t)v*N + n0 + row1];
  float psum0 = 0.f, psum1 = 0.f;

  // ---- consumer setup: wave w owns cols w*16 .. w*16+15, all 4 row-tiles ----
  const int col = w*16 + (l & 15);
  const unsigned short* bcol = hT + ((size_t)v*H + col)*N + kbase + quad*8;
  floatx4 acc[4];
  #pragma unroll
  for (int rt=0;rt<4;rt++) acc[rt] = (floatx4){0.f,0.f,0.f,0.f};

  // prefetch chunk 0
  intx4  a00 = __builtin_nontemporal_load(ap0);
  intx4  a01 = __builtin_nontemporal_load(ap0 + 1);
  intx4  a10 = __builtin_nontemporal_load(ap1);
  intx4  a11 = __builtin_nontemporal_load(ap1 + 1);
  float4 ev0 = ep[0];
  float4 ev1 = ep[1];

  const int NCH = (N/KS)/128;                 // 8 chunks
  #pragma unroll 1
  for (int c = 0; c < NCH; c++){
    const int buf = c & 1;
    // ---- produce chunk c from prefetched registers ----
    {
      float ev[8] = {ev0.x,ev0.y,ev0.z,ev0.w, ev1.x,ev1.y,ev1.z,ev1.w};
      int   aa[8] = {a00.x,a00.y,a00.z,a00.w, a01.x,a01.y,a01.z,a01.w};
      int   bb[8] = {a10.x,a10.y,a10.z,a10.w, a11.x,a11.y,a11.z,a11.w};
      float wa[8], wb[8];
      #pragma unroll
      for (int j=0;j<8;j++){
        float ya = e1r0 + ev[j];
        ya = fmaxf(ya, 0.25f*ya);             // leaky (scale-invariant) BEFORE mask
        float ea = exp2f(ya);
        wa[j] = (aa[j] > 0) ? ea : 0.f;       // masked weight exactly 0
        psum0 += wa[j];
        float yb = e1r1 + ev[j];
        yb = fmaxf(yb, 0.25f*yb);
        float eb = exp2f(yb);
        wb[j] = (bb[j] > 0) ? eb : 0.f;
        psum1 += wb[j];
      }
      union { short8 s; unsigned int u[4]; } pa, pb;
      #pragma unroll
      for (int j=0;j<4;j++){
        pa.u[j] = pk_bf16(wa[2*j], wa[2*j+1]);
        pb.u[j] = pk_bf16(wb[2*j], wb[2*j+1]);
      }
      *(short8*)&Afrag[buf][rt0  ][ksl][l][0] = pa.s;
      *(short8*)&Afrag[buf][rt0+2][ksl][l][0] = pb.s;
    }
    // ---- prefetch chunk c+1 (advance 128 ints / floats) ----
    if (c+1 < NCH){
      a00 = __builtin_nontemporal_load(ap0 + (c+1)*32);
      a01 = __builtin_nontemporal_load(ap0 + (c+1)*32 + 1);
      a10 = __builtin_nontemporal_load(ap1 + (c+1)*32);
      a11 = __builtin_nontemporal_load(ap1 + (c+1)*32 + 1);
      ev0 = ep[(c+1)*32];
      ev1 = ep[(c+1)*32 + 1];
    }
    __syncthreads();
    // ---- consume chunk c: 4 B-loads, 16 MFMAs (B reused across 4 row-tiles) ----
    #pragma unroll
    for (int ks=0; ks<4; ks++){
      short8 b8 = *(const short8*)(bcol + c*128 + ks*32);
      #pragma unroll
      for (int rt=0; rt<4; rt++){
        short8 a8 = *(const short8*)&Afrag[buf][rt][ks][l][0];
        acc[rt] = __builtin_amdgcn_mfma_f32_16x16x32_bf16(a8, b8, acc[rt], 0, 0, 0);
      }
    }
    __syncthreads();
  }
  // ---- row denominators: sum over quads (xor 16, 32), slot per ks ----
  psum0 += __shfl_xor(psum0, 16);
  psum0 += __shfl_xor(psum0, 32);
  psum1 += __shfl_xor(psum1, 16);
  psum1 += __shfl_xor(psum1, 32);
  if (l < 16){
    pden_sh[row0][ksl] = psum0;
    pden_sh[row1][ksl] = psum1;
  }
  __syncthreads();
  // ---- write partials ----
  const size_t pb = ((size_t)v*KS + ksid)*(N/M2) + blockIdx.x;
  float* pa = pacc + pb*(M2*H);
  #pragma unroll
  for (int rt=0; rt<4; rt++){
    #pragma unroll
    for (int reg=0; reg<4; reg++){
      const int row = rt*16 + quad*4 + reg;
      pa[row*H + col] = acc[rt][reg];
    }
  }
  if (t < M2){
    float den = pden_sh[t][0] + pden_sh[t][1] + pden_sh[t][2] + pden_sh[t][3];
    pdenG[pb*M2 + t] = den;
  }
}

// ---------------- K2r: combine split-K partials + epilogue ----------------
__global__ __launch_bounds__(512) void k2_reduce(
    const float* __restrict__ pacc, const float* __restrict__ pdenG,
    const float* __restrict__ mlp_out,
    const float* __restrict__ gac_b, const float* __restrict__ mlp_b,
    float* __restrict__ feat)
{
  const int v = blockIdx.y;
  const int n0 = blockIdx.x * M2;
  const int t = threadIdx.x;
  const int col = t & 127, rg = t >> 7;      // 4 row-groups of 16
  size_t pb[KS];
  #pragma unroll
  for (int k=0;k<KS;k++) pb[k] = ((size_t)v*KS + k)*(N/M2) + blockIdx.x;
  const float gb = gac_b[v*H + col];
  const float mb = mlp_b[v*H + col];
  #pragma unroll
  for (int i=0;i<16;i++){
    const int row = rg*16 + i;
    float num = 0.f, den = 0.f;
    #pragma unroll
    for (int k=0;k<KS;k++){
      num += pacc[pb[k]*(M2*H) + row*H + col];
      den += pdenG[pb[k]*M2 + row];
    }
    float x = num/den + gb;
    x = (x >= 0.f) ? x : 0.25f*x;
    const size_t idx = ((size_t)v*N + n0 + row)*H + col;
    feat[idx] = x + mlp_out[idx] + mb;
  }
}

// ---------------- K3: per-node HxH outer-product attention + fc + conf gate ----------------
#define TN3 8
__global__ __launch_bounds__(128) void k3_sgfe(
    const float* __restrict__ feat,
    const float* __restrict__ qw, const float* __restrict__ qb,
    const float* __restrict__ kw, const float* __restrict__ kb,
    const float* __restrict__ vw, const float* __restrict__ vb,
    const float* __restrict__ fcw, const float* __restrict__ fcb,
    const float* __restrict__ confw, const float* __restrict__ confb,
    float* __restrict__ feat2)
{
  const int v = blockIdx.y;
  const int n0 = blockIdx.x * TN3;
  const int t = threadIdx.x;
  const int W = t >> 6, lane = t & 63;
  __shared__ float fsT[H][12];             // feat tile transposed, padded
  __shared__ float Qs[TN3][H];
  __shared__ float2 KVs[TN3][H];
  __shared__ float As2T[H][12];            // agg, [dim][node], padded
  __shared__ float rbuf2[TN3][2];
  const float* fp = feat + ((size_t)v*N + n0)*H + t;
  #pragma unroll
  for (int r=0;r<TN3;r++) fsT[t][r] = fp[(size_t)r*H];
  __syncthreads();
  const float* qwp = qw + (size_t)v*H*H + t;
  const float* kwp = kw + (size_t)v*H*H + t;
  const float* vwp = vw + (size_t)v*H*H + t;
  float Qr[TN3], Kr[TN3], Vr[TN3];
  {
    const float qbv = qb[v*H+t], kbv = kb[v*H+t], vbv = vb[v*H+t];
    #pragma unroll
    for (int r=0;r<TN3;r++){ Qr[r]=qbv; Kr[r]=kbv; Vr[r]=vbv; }
  }
  for (int i=0;i<H;i++){   // one weight sweep computes Q,K,V for all 8 nodes
    float wq = qwp[(size_t)i*H];
    float wk = kwp[(size_t)i*H];
    float wv = vwp[(size_t)i*H];
    float4 f0 = *(const float4*)&fsT[i][0];
    float4 f1 = *(const float4*)&fsT[i][4];
    float fv[8] = {f0.x,f0.y,f0.z,f0.w, f1.x,f1.y,f1.z,f1.w};
    #pragma unroll
    for (int r=0;r<TN3;r++){
      Qr[r] = fmaf(fv[r], wq, Qr[r]);
      Kr[r] = fmaf(fv[r], wk, Kr[r]);
      Vr[r] = fmaf(fv[r], wv, Vr[r]);
    }
  }
  #pragma unroll
  for (int r=0;r<TN3;r++){
    Qs[r][t] = Qr[r];
    KVs[r][t] = make_float2(Kr[r], Vr[r]);
  }
  __syncthreads();
  // attention: wave W handles nodes r = 2*p + W; each lane covers dims lane, lane+64
  const float invs = 0.08838834764831845f;  // 1/sqrt(128)
  #pragma unroll
  for (int p=0;p<4;p++){
    const int r = 2*p + W;
    const float qa = Qs[r][lane]   * invs;
    const float qb2 = Qs[r][lane+64] * invs;
    float sA=0.f, aA=0.f, sB=0.f, aB=0.f;
    const float4* kvp = (const float4*)&KVs[r][0];
    #pragma unroll 4
    for (int oo=0; oo<H/2; oo++){
      float4 kv2 = kvp[oo];                // two (K,V) pairs per b128
      float eA0 = __expf(qa*kv2.x);  sA += eA0; aA = fmaf(eA0, kv2.y, aA);
      float eA1 = __expf(qa*kv2.z);  sA += eA1; aA = fmaf(eA1, kv2.w, aA);
      float eB0 = __expf(qb2*kv2.x); sB += eB0; aB = fmaf(eB0, kv2.y, aB);
      float eB1 = __expf(qb2*kv2.z); sB += eB1; aB = fmaf(eB1, kv2.w, aB);
    }
    As2T[lane][r]    = aA/sA;
    As2T[lane+64][r] = aB/sB;
  }
  __syncthreads();
  // fc: g[r] = sum_i As2T[i][r] * fcw[i][t]  (fcw read ONCE per block)
  const float* fcwp = fcw + (size_t)v*H*H + t;
  const float fcbv = fcb[v*H+t];
  float g[TN3];
  #pragma unroll
  for (int r=0;r<TN3;r++) g[r] = fcbv;
  for (int i=0;i<H;i++){
    float fw = fcwp[(size_t)i*H];
    float4 a0 = *(const float4*)&As2T[i][0];
    float4 a1v = *(const float4*)&As2T[i][4];
    g[0] = fmaf(a0.x, fw, g[0]);  g[1] = fmaf(a0.y, fw, g[1]);
    g[2] = fmaf(a0.z, fw, g[2]);  g[3] = fmaf(a0.w, fw, g[3]);
    g[4] = fmaf(a1v.x, fw, g[4]); g[5] = fmaf(a1v.y, fw, g[5]);
    g[6] = fmaf(a1v.z, fw, g[6]); g[7] = fmaf(a1v.w, fw, g[7]);
  }
  const float cwv = confw[v*H+t];
  const float cbv = confb[v];
  #pragma unroll
  for (int r=0;r<TN3;r++){
    g[r] = fmaxf(g[r], 0.f);
    float psm = g[r]*cwv;
    #pragma unroll
    for (int o=32;o>0;o>>=1) psm += __shfl_down(psm,o);
    if (lane==0) rbuf2[r][W] = psm;
  }
  __syncthreads();
  #pragma unroll
  for (int r=0;r<TN3;r++){
    const float conf = rbuf2[r][0] + rbuf2[r][1] + cbv;
    feat2[((size_t)v*N + n0 + r)*H + t] = g[r]*conf;
  }
}

// ---------------- K4: final classifier [N, V*H] @ [V*H, C] ----------------
__global__ __launch_bounds__(64) void k4_cls(
    const float* __restrict__ feat2,
    const float* __restrict__ mm_w, const float* __restrict__ mm_b,
    float* __restrict__ out)
{
  const int n = blockIdx.x, t = threadIdx.x;
  float a[C] = {0,0,0,0,0};
  for (int j=t; j<V*H; j+=64){
    int vv = j >> 7, hh = j & (H-1);
    float f = feat2[((size_t)vv*N + n)*H + hh];
    #pragma unroll
    for (int c=0;c<C;c++) a[c] = fmaf(f, mm_w[j*C+c], a[c]);
  }
  #pragma unroll
  for (int c=0;c<C;c++){
    #pragma unroll
    for (int o=32;o>0;o>>=1) a[c] += __shfl_down(a[c],o);
  }
  if (t==0){
    #pragma unroll
    for (int c=0;c<C;c++) out[(size_t)n*C+c] = a[c] + mm_b[c];
  }
}

extern "C" void kernel_launch(void* const* d_in, const int* in_sizes, int n_in,
                              void* d_out, int out_size, void* d_ws, size_t ws_size,
                              hipStream_t stream)
{
  (void)in_sizes; (void)n_in; (void)out_size; (void)ws_size;
  const float* data  = (const float*)d_in[0];
  const int*   adj   = (const int*)d_in[1];
  const float* gac_w = (const float*)d_in[2];
  const float* gac_b = (const float*)d_in[3];
  const float* a1    = (const float*)d_in[4];
  const float* a2    = (const float*)d_in[5];
  const float* mlp_w = (const float*)d_in[6];
  const float* mlp_b = (const float*)d_in[7];
  const float* q_w   = (const float*)d_in[8];
  const float* q_b   = (const float*)d_in[9];
  const float* k_w   = (const float*)d_in[10];
  const float* k_b   = (const float*)d_in[11];
  const float* v_w   = (const float*)d_in[12];
  const float* v_b   = (const float*)d_in[13];
  const float* fc_w  = (const float*)d_in[14];
  const float* fc_b  = (const float*)d_in[15];
  const float* cw    = (const float*)d_in[16];
  const float* cb    = (const float*)d_in[17];
  const float* mm_w  = (const float*)d_in[18];
  const float* mm_b  = (const float*)d_in[19];

  float* ws = (float*)d_ws;
  const size_t VNH = (size_t)V*N*H;
  float* mlp   = ws;
  float* feat  = ws + VNH;
  float* feat2 = ws + 2*VNH;
  float* e1    = ws + 3*VNH;
  float* e2    = e1 + (size_t)V*N;
  unsigned short* hT = (unsigned short*)(e2 + (size_t)V*N);  // [V][H][N] bf16
  float* pacc  = (float*)(hT + VNH);                         // [V][KS][N/M2][M2][H]
  float* pden  = pacc + (size_t)V*KS*(N/M2)*M2*H;            // [V][KS][N/M2][M2]

  k1_gemm<<<dim3(N/TN1, V), 256, 0, stream>>>(data, gac_w, mlp_w, a1, a2,
                                              hT, mlp, e1, e2);
  k2_attn<<<dim3(N/M2, KS, V), 512, 0, stream>>>(hT, adj, e1, e2, pacc, pden);
  k2_reduce<<<dim3(N/M2, V), 512, 0, stream>>>(pacc, pden, mlp, gac_b, mlp_b, feat);
  k3_sgfe<<<dim3(N/TN3, V), 128, 0, stream>>>(feat, q_w, q_b, k_w, k_b, v_w, v_b,
                                              fc_w, fc_b, cw, cb, feat2);
  k4_cls<<<dim3(N),          64, 0, stream>>>(feat2, mm_w, mm_b, (float*)d_out);
}

// Round 11
// 447.322 us; speedup vs baseline: 1.1739x; 1.0625x over previous
//
#include <hip/hip_runtime.h>
#include <hip/hip_bf16.h>

#define V 3
#define N 4096
#define D 512
#define H 128
#define C 5
#define KS 4                    // split-K factor for k2
#define M2 64                   // rows per k2 block
#define M1 32                   // rows per k1 block
#define LOG2E 1.4426950408889634f

typedef short short8 __attribute__((ext_vector_type(8)));
typedef float floatx4 __attribute__((ext_vector_type(4)));
typedef int   intx4  __attribute__((ext_vector_type(4)));

__device__ __forceinline__ unsigned short f2bf(float f){
  __hip_bfloat16 h = __float2bfloat16(f);
  return *reinterpret_cast<unsigned short*>(&h);
}
// RNE pack of two non-NaN floats to packed bf16x2
__device__ __forceinline__ unsigned int pk_bf16(float a, float b){
  unsigned int ua = __float_as_uint(a), ub = __float_as_uint(b);
  ua += 0x7FFFu + ((ua >> 16) & 1u);
  ub += 0x7FFFu + ((ub >> 16) & 1u);
  return (ua >> 16) | (ub & 0xFFFF0000u);
}

// ---------------- K0: weight transpose gac_w/mlp_w -> wT[mat][v][col][k] bf16 ----------------
__global__ __launch_bounds__(256) void k0_wt(
    const float* __restrict__ gw, const float* __restrict__ mw,
    unsigned short* __restrict__ wT)
{
  const int v = blockIdx.x, m = blockIdx.y, kc = blockIdx.z;  // k-chunk of 64
  const int t = threadIdx.x;
  __shared__ unsigned short tr[128*72];     // [col][kk], pad 72 vs 64
  const float* src = (m ? mw : gw) + (size_t)v*D*H + (size_t)kc*64*H;
  for (int i = t; i < 64*128; i += 256){
    int kk = i >> 7, col = i & 127;
    tr[col*72 + kk] = f2bf(src[i]);
  }
  __syncthreads();
  const int col = t >> 1, half = t & 1;
  uint4* dst = (uint4*)(wT + (((size_t)m*V + v)*H + col)*D + kc*64 + half*32);
  const unsigned short* s = &tr[col*72 + half*32];
  dst[0] = *(const uint4*)(s);
  dst[1] = *(const uint4*)(s + 8);
  dst[2] = *(const uint4*)(s + 16);
  dst[3] = *(const uint4*)(s + 24);
}

// ---------------- K1: MFMA dual-GEMM h=data@gac_w, mlp=data@mlp_w ----------------
// 32 rows/block, 512 thr. A (data, fp32->bf16) staged fragment-ordered in LDS;
// B from wT (contiguous-k, same pattern as k2's hT). Waves 0-3: gac (h->hT bf16,
// e1/e2 from fp32 acc); waves 4-7: mlp (fp32 out). Fragment layouts = k2-verified.
__global__ __launch_bounds__(512) void k1_gemm(
    const float* __restrict__ data, const unsigned short* __restrict__ wT,
    const float* __restrict__ a1, const float* __restrict__ a2,
    unsigned short* __restrict__ hT, float* __restrict__ mlp_out,
    float* __restrict__ e1g, float* __restrict__ e2g)
{
  const int v = blockIdx.y;
  const int n0 = blockIdx.x * M1;
  const int t = threadIdx.x;
  const int w = t >> 6, l = t & 63;
  __shared__ __align__(16) unsigned short AT[2][16][64][8];   // 32 KB
  __shared__ float epart[2][M1][4];
  unsigned short* hTile = &AT[0][0][0][0];    // aliased post-MFMA: [128][40]

  // ---- producer: stage A fragments (each thread: 1 row x 32 k, contiguous loads) ----
  {
    const int r = t >> 4, oct = t & 15;       // row in block, kstep
    const float4* dp = (const float4*)(data + ((size_t)v*N + n0 + r)*D + oct*32);
    float4 f[8];
    #pragma unroll
    for (int i=0;i<8;i++) f[i] = dp[i];
    #pragma unroll
    for (int q=0;q<4;q++){
      uint4 u;
      u.x = pk_bf16(f[2*q].x,   f[2*q].y);
      u.y = pk_bf16(f[2*q].z,   f[2*q].w);
      u.z = pk_bf16(f[2*q+1].x, f[2*q+1].y);
      u.w = pk_bf16(f[2*q+1].z, f[2*q+1].w);
      *(uint4*)&AT[r>>4][oct][(r&15) + 16*q][0] = u;
    }
  }
  __syncthreads();
  // ---- consumer: wave w -> mat m (0=gac,1=mlp), cols cb..cb+31 ----
  const int m = w >> 2, cb = (w & 3)*32;
  const int quad = l >> 4, c16 = l & 15;
  const unsigned short* b0 = wT + (((size_t)m*V + v)*H + cb + c16)*D + quad*8;
  floatx4 acc[2][2];
  #pragma unroll
  for (int rt=0;rt<2;rt++) for (int c=0;c<2;c++) acc[rt][c] = (floatx4){0.f,0.f,0.f,0.f};
  #pragma unroll
  for (int ks=0; ks<16; ks++){
    short8 a0 = *(const short8*)&AT[0][ks][l][0];
    short8 a1f = *(const short8*)&AT[1][ks][l][0];
    short8 bb0 = *(const short8*)(b0 + ks*32);
    short8 bb1 = *(const short8*)(b0 + 16*D + ks*32);
    acc[0][0] = __builtin_amdgcn_mfma_f32_16x16x32_bf16(a0,  bb0, acc[0][0], 0,0,0);
    acc[1][0] = __builtin_amdgcn_mfma_f32_16x16x32_bf16(a1f, bb0, acc[1][0], 0,0,0);
    acc[0][1] = __builtin_amdgcn_mfma_f32_16x16x32_bf16(a0,  bb1, acc[0][1], 0,0,0);
    acc[1][1] = __builtin_amdgcn_mfma_f32_16x16x32_bf16(a1f, bb1, acc[1][1], 0,0,0);
  }
  if (m == 1){
    // mlp: raw fp32 (mlp_b added in k3's fused epilogue)
    #pragma unroll
    for (int rt=0;rt<2;rt++)
      #pragma unroll
      for (int c=0;c<2;c++)
        #pragma unroll
        for (int reg=0;reg<4;reg++){
          const int row = rt*16 + quad*4 + reg, col = cb + c*16 + c16;
          mlp_out[((size_t)v*N + n0 + row)*H + col] = acc[rt][c][reg];
        }
  } else {
    // e1/e2 partials from fp32 acc (matches prior fp32-h behavior)
    const float a1v0 = a1[v*H + cb + c16],      a2v0 = a2[v*H + cb + c16];
    const float a1v1 = a1[v*H + cb + 16 + c16], a2v1 = a2[v*H + cb + 16 + c16];
    #pragma unroll
    for (int rt=0;rt<2;rt++)
      #pragma unroll
      for (int reg=0;reg<4;reg++){
        float p1 = acc[rt][0][reg]*a1v0 + acc[rt][1][reg]*a1v1;
        float p2 = acc[rt][0][reg]*a2v0 + acc[rt][1][reg]*a2v1;
        p1 += __shfl_xor(p1,1); p1 += __shfl_xor(p1,2);
        p1 += __shfl_xor(p1,4); p1 += __shfl_xor(p1,8);
        p2 += __shfl_xor(p2,1); p2 += __shfl_xor(p2,2);
        p2 += __shfl_xor(p2,4); p2 += __shfl_xor(p2,8);
        if (c16 == 0){
          epart[0][rt*16 + quad*4 + reg][w] = p1;
          epart[1][rt*16 + quad*4 + reg][w] = p2;
        }
      }
  }
  __syncthreads();                            // AT reads done -> safe to alias hTile
  if (m == 0){
    #pragma unroll
    for (int rt=0;rt<2;rt++)
      #pragma unroll
      for (int c=0;c<2;c++)
        #pragma unroll
        for (int reg=0;reg<4;reg++){
          const int row = rt*16 + quad*4 + reg, col = cb + c*16 + c16;
          hTile[col*40 + row] = f2bf(acc[rt][c][reg]);
        }
  }
  __syncthreads();
  if (t < 128){
    const unsigned short* s = &hTile[t*40];
    uint4* dst = (uint4*)(hT + ((size_t)v*H + t)*N + n0);
    dst[0] = *(const uint4*)(s);
    dst[1] = *(const uint4*)(s + 8);
    dst[2] = *(const uint4*)(s + 16);
    dst[3] = *(const uint4*)(s + 24);
  } else if (t < 128 + M1){
    const int r = t - 128;
    e1g[(size_t)v*N + n0 + r] = LOG2E*(epart[0][r][0]+epart[0][r][1]+epart[0][r][2]+epart[0][r][3]);
  } else if (t < 128 + 2*M1){
    const int r = t - 128 - M1;
    e2g[(size_t)v*N + n0 + r] = LOG2E*(epart[1][r][0]+epart[1][r][1]+epart[1][r][2]+epart[1][r][3]);
  }
}

// ---------------- K2: masked graph attention via bf16 MFMA (r10, unchanged) ----------------
__global__ __launch_bounds__(512, 4) void k2_attn(
    const unsigned short* __restrict__ hT, const int* __restrict__ adj,
    const float* __restrict__ e1g, const float* __restrict__ e2g,   // pre-scaled by log2e
    float* __restrict__ pacc, float* __restrict__ pdenG)
{
  const int v = blockIdx.z;
  const int ksid = blockIdx.y;
  const int n0 = blockIdx.x * M2;
  const int kbase = ksid * (N/KS);
  const int t = threadIdx.x;
  const int w = t >> 6, l = t & 63;
  __shared__ __align__(16) unsigned short Afrag[2][4][4][64][8];
  __shared__ float pden_sh[M2][4];

  const int ksl  = w & 3;
  const int quad = l >> 4;
  const int rt0  = w >> 2;
  const int row0 = rt0*16 + (l & 15);
  const int row1 = row0 + 32;
  const int koff = ksl*32 + quad*8;
  const intx4* ap0 = (const intx4*)(adj + ((size_t)v*N + n0 + row0)*N + kbase + koff);
  const intx4* ap1 = (const intx4*)(adj + ((size_t)v*N + n0 + row1)*N + kbase + koff);
  const float4* ep = (const float4*)(e2g + (size_t)v*N + kbase + koff);
  const float e1r0 = e1g[(size_t)v*N + n0 + row0];
  const float e1r1 = e1g[(size_t)v*N + n0 + row1];
  float psum0 = 0.f, psum1 = 0.f;

  const int col = w*16 + (l & 15);
  const unsigned short* bcol = hT + ((size_t)v*H + col)*N + kbase + quad*8;
  floatx4 acc[4];
  #pragma unroll
  for (int rt=0;rt<4;rt++) acc[rt] = (floatx4){0.f,0.f,0.f,0.f};

  intx4  a00 = __builtin_nontemporal_load(ap0);
  intx4  a01 = __builtin_nontemporal_load(ap0 + 1);
  intx4  a10 = __builtin_nontemporal_load(ap1);
  intx4  a11 = __builtin_nontemporal_load(ap1 + 1);
  float4 ev0 = ep[0];
  float4 ev1 = ep[1];

  const int NCH = (N/KS)/128;
  #pragma unroll 1
  for (int c = 0; c < NCH; c++){
    const int buf = c & 1;
    {
      float ev[8] = {ev0.x,ev0.y,ev0.z,ev0.w, ev1.x,ev1.y,ev1.z,ev1.w};
      int   aa[8] = {a00.x,a00.y,a00.z,a00.w, a01.x,a01.y,a01.z,a01.w};
      int   bb[8] = {a10.x,a10.y,a10.z,a10.w, a11.x,a11.y,a11.z,a11.w};
      float wa[8], wb[8];
      #pragma unroll
      for (int j=0;j<8;j++){
        float ya = e1r0 + ev[j];
        ya = fmaxf(ya, 0.25f*ya);
        float ea = exp2f(ya);
        wa[j] = (aa[j] > 0) ? ea : 0.f;
        psum0 += wa[j];
        float yb = e1r1 + ev[j];
        yb = fmaxf(yb, 0.25f*yb);
        float eb = exp2f(yb);
        wb[j] = (bb[j] > 0) ? eb : 0.f;
        psum1 += wb[j];
      }
      union { short8 s; unsigned int u[4]; } pa, pb;
      #pragma unroll
      for (int j=0;j<4;j++){
        pa.u[j] = pk_bf16(wa[2*j], wa[2*j+1]);
        pb.u[j] = pk_bf16(wb[2*j], wb[2*j+1]);
      }
      *(short8*)&Afrag[buf][rt0  ][ksl][l][0] = pa.s;
      *(short8*)&Afrag[buf][rt0+2][ksl][l][0] = pb.s;
    }
    if (c+1 < NCH){
      a00 = __builtin_nontemporal_load(ap0 + (c+1)*32);
      a01 = __builtin_nontemporal_load(ap0 + (c+1)*32 + 1);
      a10 = __builtin_nontemporal_load(ap1 + (c+1)*32);
      a11 = __builtin_nontemporal_load(ap1 + (c+1)*32 + 1);
      ev0 = ep[(c+1)*32];
      ev1 = ep[(c+1)*32 + 1];
    }
    __syncthreads();
    #pragma unroll
    for (int ks=0; ks<4; ks++){
      short8 b8 = *(const short8*)(bcol + c*128 + ks*32);
      #pragma unroll
      for (int rt=0; rt<4; rt++){
        short8 a8 = *(const short8*)&Afrag[buf][rt][ks][l][0];
        acc[rt] = __builtin_amdgcn_mfma_f32_16x16x32_bf16(a8, b8, acc[rt], 0, 0, 0);
      }
    }
    __syncthreads();
  }
  psum0 += __shfl_xor(psum0, 16);
  psum0 += __shfl_xor(psum0, 32);
  psum1 += __shfl_xor(psum1, 16);
  psum1 += __shfl_xor(psum1, 32);
  if (l < 16){
    pden_sh[row0][ksl] = psum0;
    pden_sh[row1][ksl] = psum1;
  }
  __syncthreads();
  const size_t pb = ((size_t)v*KS + ksid)*(N/M2) + blockIdx.x;
  float* pa = pacc + pb*(M2*H);
  #pragma unroll
  for (int rt=0; rt<4; rt++){
    #pragma unroll
    for (int reg=0; reg<4; reg++){
      const int row = rt*16 + quad*4 + reg;
      pa[row*H + col] = acc[rt][reg];
    }
  }
  if (t < M2){
    float den = pden_sh[t][0] + pden_sh[t][1] + pden_sh[t][2] + pden_sh[t][3];
    pdenG[pb*M2 + t] = den;
  }
}

// ---------------- K3: split-K combine + GAC epilogue fused, then SGFE ----------------
#define TN3 8
__global__ __launch_bounds__(128) void k3_sgfe(
    const float* __restrict__ pacc, const float* __restrict__ pdenG,
    const float* __restrict__ mlp_out,
    const float* __restrict__ gac_b, const float* __restrict__ mlp_b,
    const float* __restrict__ qw, const float* __restrict__ qb,
    const float* __restrict__ kw, const float* __restrict__ kb,
    const float* __restrict__ vw, const float* __restrict__ vb,
    const float* __restrict__ fcw, const float* __restrict__ fcb,
    const float* __restrict__ confw, const float* __restrict__ confb,
    float* __restrict__ feat2)
{
  const int v = blockIdx.y;
  const int n0 = blockIdx.x * TN3;
  const int t = threadIdx.x;
  const int W = t >> 6, lane = t & 63;
  __shared__ float fsT[H][12];             // feat tile transposed, padded
  __shared__ float Qs[TN3][H];
  __shared__ float2 KVs[TN3][H];
  __shared__ float As2T[H][12];
  __shared__ float rbuf2[TN3][2];
  // ---- fused k2-reduce epilogue: build feat tile directly from pacc/pden ----
  {
    const int bx2 = blockIdx.x >> 3;           // n0/64
    const int lr0 = (blockIdx.x & 7) * TN3;    // row offset within 64-row k2 block
    const float gbv = gac_b[v*H + t];
    const float mbv = mlp_b[v*H + t];
    #pragma unroll
    for (int r=0;r<TN3;r++){
      float num = 0.f, den = 0.f;
      #pragma unroll
      for (int ks=0;ks<KS;ks++){
        const size_t pb = ((size_t)v*KS + ks)*(N/M2) + bx2;
        num += pacc[pb*(M2*H) + (size_t)(lr0 + r)*H + t];
        den += pdenG[pb*M2 + lr0 + r];
      }
      float x = num/den + gbv;
      x = (x >= 0.f) ? x : 0.25f*x;
      x += mlp_out[((size_t)v*N + n0 + r)*H + t] + mbv;
      fsT[t][r] = x;
    }
  }
  __syncthreads();
  const float* qwp = qw + (size_t)v*H*H + t;
  const float* kwp = kw + (size_t)v*H*H + t;
  const float* vwp = vw + (size_t)v*H*H + t;
  float Qr[TN3], Kr[TN3], Vr[TN3];
  {
    const float qbv = qb[v*H+t], kbv = kb[v*H+t], vbv = vb[v*H+t];
    #pragma unroll
    for (int r=0;r<TN3;r++){ Qr[r]=qbv; Kr[r]=kbv; Vr[r]=vbv; }
  }
  for (int i=0;i<H;i++){
    float wq = qwp[(size_t)i*H];
    float wk = kwp[(size_t)i*H];
    float wv = vwp[(size_t)i*H];
    float4 f0 = *(const float4*)&fsT[i][0];
    float4 f1 = *(const float4*)&fsT[i][4];
    float fv[8] = {f0.x,f0.y,f0.z,f0.w, f1.x,f1.y,f1.z,f1.w};
    #pragma unroll
    for (int r=0;r<TN3;r++){
      Qr[r] = fmaf(fv[r], wq, Qr[r]);
      Kr[r] = fmaf(fv[r], wk, Kr[r]);
      Vr[r] = fmaf(fv[r], wv, Vr[r]);
    }
  }
  #pragma unroll
  for (int r=0;r<TN3;r++){
    Qs[r][t] = Qr[r];
    KVs[r][t] = make_float2(Kr[r], Vr[r]);
  }
  __syncthreads();
  const float invs = 0.08838834764831845f;  // 1/sqrt(128)
  #pragma unroll
  for (int p=0;p<4;p++){
    const int r = 2*p + W;
    const float qa = Qs[r][lane]   * invs;
    const float qb2 = Qs[r][lane+64] * invs;
    float sA=0.f, aA=0.f, sB=0.f, aB=0.f;
    const float4* kvp = (const float4*)&KVs[r][0];
    #pragma unroll 4
    for (int oo=0; oo<H/2; oo++){
      float4 kv2 = kvp[oo];
      float eA0 = __expf(qa*kv2.x);  sA += eA0; aA = fmaf(eA0, kv2.y, aA);
      float eA1 = __expf(qa*kv2.z);  sA += eA1; aA = fmaf(eA1, kv2.w, aA);
      float eB0 = __expf(qb2*kv2.x); sB += eB0; aB = fmaf(eB0, kv2.y, aB);
      float eB1 = __expf(qb2*kv2.z); sB += eB1; aB = fmaf(eB1, kv2.w, aB);
    }
    As2T[lane][r]    = aA/sA;
    As2T[lane+64][r] = aB/sB;
  }
  __syncthreads();
  const float* fcwp = fcw + (size_t)v*H*H + t;
  const float fcbv = fcb[v*H+t];
  float g[TN3];
  #pragma unroll
  for (int r=0;r<TN3;r++) g[r] = fcbv;
  for (int i=0;i<H;i++){
    float fw = fcwp[(size_t)i*H];
    float4 a0 = *(const float4*)&As2T[i][0];
    float4 a1v = *(const float4*)&As2T[i][4];
    g[0] = fmaf(a0.x, fw, g[0]);  g[1] = fmaf(a0.y, fw, g[1]);
    g[2] = fmaf(a0.z, fw, g[2]);  g[3] = fmaf(a0.w, fw, g[3]);
    g[4] = fmaf(a1v.x, fw, g[4]); g[5] = fmaf(a1v.y, fw, g[5]);
    g[6] = fmaf(a1v.z, fw, g[6]); g[7] = fmaf(a1v.w, fw, g[7]);
  }
  const float cwv = confw[v*H+t];
  const float cbv = confb[v];
  #pragma unroll
  for (int r=0;r<TN3;r++){
    g[r] = fmaxf(g[r], 0.f);
    float psm = g[r]*cwv;
    #pragma unroll
    for (int o=32;o>0;o>>=1) psm += __shfl_down(psm,o);
    if (lane==0) rbuf2[r][W] = psm;
  }
  __syncthreads();
  #pragma unroll
  for (int r=0;r<TN3;r++){
    const float conf = rbuf2[r][0] + rbuf2[r][1] + cbv;
    feat2[((size_t)v*N + n0 + r)*H + t] = g[r]*conf;
  }
}

// ---------------- K4: final classifier [N, V*H] @ [V*H, C] ----------------
__global__ __launch_bounds__(64) void k4_cls(
    const float* __restrict__ feat2,
    const float* __restrict__ mm_w, const float* __restrict__ mm_b,
    float* __restrict__ out)
{
  const int n = blockIdx.x, t = threadIdx.x;
  float a[C] = {0,0,0,0,0};
  for (int j=t; j<V*H; j+=64){
    int vv = j >> 7, hh = j & (H-1);
    float f = feat2[((size_t)vv*N + n)*H + hh];
    #pragma unroll
    for (int c=0;c<C;c++) a[c] = fmaf(f, mm_w[j*C+c], a[c]);
  }
  #pragma unroll
  for (int c=0;c<C;c++){
    #pragma unroll
    for (int o=32;o>0;o>>=1) a[c] += __shfl_down(a[c],o);
  }
  if (t==0){
    #pragma unroll
    for (int c=0;c<C;c++) out[(size_t)n*C+c] = a[c] + mm_b[c];
  }
}

extern "C" void kernel_launch(void* const* d_in, const int* in_sizes, int n_in,
                              void* d_out, int out_size, void* d_ws, size_t ws_size,
                              hipStream_t stream)
{
  (void)in_sizes; (void)n_in; (void)out_size; (void)ws_size;
  const float* data  = (const float*)d_in[0];
  const int*   adj   = (const int*)d_in[1];
  const float* gac_w = (const float*)d_in[2];
  const float* gac_b = (const float*)d_in[3];
  const float* a1    = (const float*)d_in[4];
  const float* a2    = (const float*)d_in[5];
  const float* mlp_w = (const float*)d_in[6];
  const float* mlp_b = (const float*)d_in[7];
  const float* q_w   = (const float*)d_in[8];
  const float* q_b   = (const float*)d_in[9];
  const float* k_w   = (const float*)d_in[10];
  const float* k_b   = (const float*)d_in[11];
  const float* v_w   = (const float*)d_in[12];
  const float* v_b   = (const float*)d_in[13];
  const float* fc_w  = (const float*)d_in[14];
  const float* fc_b  = (const float*)d_in[15];
  const float* cw    = (const float*)d_in[16];
  const float* cb    = (const float*)d_in[17];
  const float* mm_w  = (const float*)d_in[18];
  const float* mm_b  = (const float*)d_in[19];

  float* ws = (float*)d_ws;
  const size_t VNH = (size_t)V*N*H;
  float* mlp   = ws;
  float* feat2 = ws + VNH;
  float* e1    = ws + 2*VNH;
  float* e2    = e1 + (size_t)V*N;
  unsigned short* hT = (unsigned short*)(e2 + (size_t)V*N);  // [V][H][N] bf16
  unsigned short* wT = hT + VNH;                             // [2][V][H][D] bf16
  float* pacc  = (float*)(wT + (size_t)2*V*H*D);             // [V][KS][N/M2][M2][H]
  float* pden  = pacc + (size_t)V*KS*(N/M2)*M2*H;            // [V][KS][N/M2][M2]

  k0_wt  <<<dim3(V, 2, D/64), 256, 0, stream>>>(gac_w, mlp_w, wT);
  k1_gemm<<<dim3(N/M1, V),    512, 0, stream>>>(data, wT, a1, a2, hT, mlp, e1, e2);
  k2_attn<<<dim3(N/M2, KS, V),512, 0, stream>>>(hT, adj, e1, e2, pacc, pden);
  k3_sgfe<<<dim3(N/TN3, V),   128, 0, stream>>>(pacc, pden, mlp, gac_b, mlp_b,
                                                q_w, q_b, k_w, k_b, v_w, v_b,
                                                fc_w, fc_b, cw, cb, feat2);
  k4_cls <<<dim3(N),           64, 0, stream>>>(feat2, mm_w, mm_b, (float*)d_out);
}

// Round 12
// 430.074 us; speedup vs baseline: 1.2209x; 1.0401x over previous
//
#include <hip/hip_runtime.h>
#include <hip/hip_bf16.h>

#define V 3
#define N 4096
#define D 512
#define H 128
#define C 5
#define KS 4                    // split-K factor for k2
#define M2 64                   // rows per k2 block
#define M1 32                   // rows per k1 block
#define LOG2E 1.4426950408889634f

typedef short short8 __attribute__((ext_vector_type(8)));
typedef float floatx4 __attribute__((ext_vector_type(4)));
typedef int   intx4  __attribute__((ext_vector_type(4)));

__device__ __forceinline__ unsigned short f2bf(float f){
  __hip_bfloat16 h = __float2bfloat16(f);
  return *reinterpret_cast<unsigned short*>(&h);
}
// RNE pack of two non-NaN floats to packed bf16x2
__device__ __forceinline__ unsigned int pk_bf16(float a, float b){
  unsigned int ua = __float_as_uint(a), ub = __float_as_uint(b);
  ua += 0x7FFFu + ((ua >> 16) & 1u);
  ub += 0x7FFFu + ((ub >> 16) & 1u);
  return (ua >> 16) | (ub & 0xFFFF0000u);
}

// ---------------- K0: weight transpose gac_w/mlp_w -> wT[mat][v][col][k] bf16 ----------------
__global__ __launch_bounds__(256) void k0_wt(
    const float* __restrict__ gw, const float* __restrict__ mw,
    unsigned short* __restrict__ wT)
{
  const int v = blockIdx.x, m = blockIdx.y, kc = blockIdx.z;  // k-chunk of 64
  const int t = threadIdx.x;
  __shared__ unsigned short tr[128*72];
  const float* src = (m ? mw : gw) + (size_t)v*D*H + (size_t)kc*64*H;
  for (int i = t; i < 64*128; i += 256){
    int kk = i >> 7, col = i & 127;
    tr[col*72 + kk] = f2bf(src[i]);
  }
  __syncthreads();
  const int col = t >> 1, half = t & 1;
  uint4* dst = (uint4*)(wT + (((size_t)m*V + v)*H + col)*D + kc*64 + half*32);
  const unsigned short* s = &tr[col*72 + half*32];
  dst[0] = *(const uint4*)(s);
  dst[1] = *(const uint4*)(s + 8);
  dst[2] = *(const uint4*)(s + 16);
  dst[3] = *(const uint4*)(s + 24);
}

// ---------------- K0b: transpose q/k/v/fc weights -> wq4T[4][v][col][k] bf16 ----------------
__global__ __launch_bounds__(256) void k0b_wt(
    const float* __restrict__ qw, const float* __restrict__ kw,
    const float* __restrict__ vw, const float* __restrict__ fw,
    unsigned short* __restrict__ wq4T)
{
  const int v = blockIdx.x, m = blockIdx.y, kc = blockIdx.z;  // kc 0..1
  const int t = threadIdx.x;
  __shared__ unsigned short tr[128*72];
  const float* src = (m==0?qw: m==1?kw: m==2?vw: fw) + (size_t)v*H*H + (size_t)kc*64*H;
  for (int i = t; i < 64*128; i += 256){
    int kk = i >> 7, col = i & 127;
    tr[col*72 + kk] = f2bf(src[i]);
  }
  __syncthreads();
  const int col = t >> 1, half = t & 1;
  uint4* dst = (uint4*)(wq4T + (((size_t)m*V + v)*H + col)*H + kc*64 + half*32);
  const unsigned short* s = &tr[col*72 + half*32];
  dst[0] = *(const uint4*)(s);
  dst[1] = *(const uint4*)(s + 8);
  dst[2] = *(const uint4*)(s + 16);
  dst[3] = *(const uint4*)(s + 24);
}

// ---------------- K1: MFMA dual-GEMM h=data@gac_w, mlp=data@mlp_w (r11, proven) ----------------
__global__ __launch_bounds__(512) void k1_gemm(
    const float* __restrict__ data, const unsigned short* __restrict__ wT,
    const float* __restrict__ a1, const float* __restrict__ a2,
    unsigned short* __restrict__ hT, float* __restrict__ mlp_out,
    float* __restrict__ e1g, float* __restrict__ e2g)
{
  const int v = blockIdx.y;
  const int n0 = blockIdx.x * M1;
  const int t = threadIdx.x;
  const int w = t >> 6, l = t & 63;
  __shared__ __align__(16) unsigned short AT[2][16][64][8];
  __shared__ float epart[2][M1][4];
  unsigned short* hTile = &AT[0][0][0][0];

  {
    const int r = t >> 4, oct = t & 15;
    const float4* dp = (const float4*)(data + ((size_t)v*N + n0 + r)*D + oct*32);
    float4 f[8];
    #pragma unroll
    for (int i=0;i<8;i++) f[i] = dp[i];
    #pragma unroll
    for (int q=0;q<4;q++){
      uint4 u;
      u.x = pk_bf16(f[2*q].x,   f[2*q].y);
      u.y = pk_bf16(f[2*q].z,   f[2*q].w);
      u.z = pk_bf16(f[2*q+1].x, f[2*q+1].y);
      u.w = pk_bf16(f[2*q+1].z, f[2*q+1].w);
      *(uint4*)&AT[r>>4][oct][(r&15) + 16*q][0] = u;
    }
  }
  __syncthreads();
  const int m = w >> 2, cb = (w & 3)*32;
  const int quad = l >> 4, c16 = l & 15;
  const unsigned short* b0 = wT + (((size_t)m*V + v)*H + cb + c16)*D + quad*8;
  floatx4 acc[2][2];
  #pragma unroll
  for (int rt=0;rt<2;rt++) for (int c=0;c<2;c++) acc[rt][c] = (floatx4){0.f,0.f,0.f,0.f};
  #pragma unroll
  for (int ks=0; ks<16; ks++){
    short8 a0 = *(const short8*)&AT[0][ks][l][0];
    short8 a1f = *(const short8*)&AT[1][ks][l][0];
    short8 bb0 = *(const short8*)(b0 + ks*32);
    short8 bb1 = *(const short8*)(b0 + 16*D + ks*32);
    acc[0][0] = __builtin_amdgcn_mfma_f32_16x16x32_bf16(a0,  bb0, acc[0][0], 0,0,0);
    acc[1][0] = __builtin_amdgcn_mfma_f32_16x16x32_bf16(a1f, bb0, acc[1][0], 0,0,0);
    acc[0][1] = __builtin_amdgcn_mfma_f32_16x16x32_bf16(a0,  bb1, acc[0][1], 0,0,0);
    acc[1][1] = __builtin_amdgcn_mfma_f32_16x16x32_bf16(a1f, bb1, acc[1][1], 0,0,0);
  }
  if (m == 1){
    #pragma unroll
    for (int rt=0;rt<2;rt++)
      #pragma unroll
      for (int c=0;c<2;c++)
        #pragma unroll
        for (int reg=0;reg<4;reg++){
          const int row = rt*16 + quad*4 + reg, col = cb + c*16 + c16;
          mlp_out[((size_t)v*N + n0 + row)*H + col] = acc[rt][c][reg];
        }
  } else {
    const float a1v0 = a1[v*H + cb + c16],      a2v0 = a2[v*H + cb + c16];
    const float a1v1 = a1[v*H + cb + 16 + c16], a2v1 = a2[v*H + cb + 16 + c16];
    #pragma unroll
    for (int rt=0;rt<2;rt++)
      #pragma unroll
      for (int reg=0;reg<4;reg++){
        float p1 = acc[rt][0][reg]*a1v0 + acc[rt][1][reg]*a1v1;
        float p2 = acc[rt][0][reg]*a2v0 + acc[rt][1][reg]*a2v1;
        p1 += __shfl_xor(p1,1); p1 += __shfl_xor(p1,2);
        p1 += __shfl_xor(p1,4); p1 += __shfl_xor(p1,8);
        p2 += __shfl_xor(p2,1); p2 += __shfl_xor(p2,2);
        p2 += __shfl_xor(p2,4); p2 += __shfl_xor(p2,8);
        if (c16 == 0){
          epart[0][rt*16 + quad*4 + reg][w] = p1;
          epart[1][rt*16 + quad*4 + reg][w] = p2;
        }
      }
  }
  __syncthreads();
  if (m == 0){
    #pragma unroll
    for (int rt=0;rt<2;rt++)
      #pragma unroll
      for (int c=0;c<2;c++)
        #pragma unroll
        for (int reg=0;reg<4;reg++){
          const int row = rt*16 + quad*4 + reg, col = cb + c*16 + c16;
          hTile[col*40 + row] = f2bf(acc[rt][c][reg]);
        }
  }
  __syncthreads();
  if (t < 128){
    const unsigned short* s = &hTile[t*40];
    uint4* dst = (uint4*)(hT + ((size_t)v*H + t)*N + n0);
    dst[0] = *(const uint4*)(s);
    dst[1] = *(const uint4*)(s + 8);
    dst[2] = *(const uint4*)(s + 16);
    dst[3] = *(const uint4*)(s + 24);
  } else if (t < 128 + M1){
    const int r = t - 128;
    e1g[(size_t)v*N + n0 + r] = LOG2E*(epart[0][r][0]+epart[0][r][1]+epart[0][r][2]+epart[0][r][3]);
  } else if (t < 128 + 2*M1){
    const int r = t - 128 - M1;
    e2g[(size_t)v*N + n0 + r] = LOG2E*(epart[1][r][0]+epart[1][r][1]+epart[1][r][2]+epart[1][r][3]);
  }
}

// ---------------- K2: masked graph attention via bf16 MFMA (r10, proven) ----------------
__global__ __launch_bounds__(512, 4) void k2_attn(
    const unsigned short* __restrict__ hT, const int* __restrict__ adj,
    const float* __restrict__ e1g, const float* __restrict__ e2g,
    float* __restrict__ pacc, float* __restrict__ pdenG)
{
  const int v = blockIdx.z;
  const int ksid = blockIdx.y;
  const int n0 = blockIdx.x * M2;
  const int kbase = ksid * (N/KS);
  const int t = threadIdx.x;
  const int w = t >> 6, l = t & 63;
  __shared__ __align__(16) unsigned short Afrag[2][4][4][64][8];
  __shared__ float pden_sh[M2][4];

  const int ksl  = w & 3;
  const int quad = l >> 4;
  const int rt0  = w >> 2;
  const int row0 = rt0*16 + (l & 15);
  const int row1 = row0 + 32;
  const int koff = ksl*32 + quad*8;
  const intx4* ap0 = (const intx4*)(adj + ((size_t)v*N + n0 + row0)*N + kbase + koff);
  const intx4* ap1 = (const intx4*)(adj + ((size_t)v*N + n0 + row1)*N + kbase + koff);
  const float4* ep = (const float4*)(e2g + (size_t)v*N + kbase + koff);
  const float e1r0 = e1g[(size_t)v*N + n0 + row0];
  const float e1r1 = e1g[(size_t)v*N + n0 + row1];
  float psum0 = 0.f, psum1 = 0.f;

  const int col = w*16 + (l & 15);
  const unsigned short* bcol = hT + ((size_t)v*H + col)*N + kbase + quad*8;
  floatx4 acc[4];
  #pragma unroll
  for (int rt=0;rt<4;rt++) acc[rt] = (floatx4){0.f,0.f,0.f,0.f};

  intx4  a00 = __builtin_nontemporal_load(ap0);
  intx4  a01 = __builtin_nontemporal_load(ap0 + 1);
  intx4  a10 = __builtin_nontemporal_load(ap1);
  intx4  a11 = __builtin_nontemporal_load(ap1 + 1);
  float4 ev0 = ep[0];
  float4 ev1 = ep[1];

  const int NCH = (N/KS)/128;
  #pragma unroll 1
  for (int c = 0; c < NCH; c++){
    const int buf = c & 1;
    {
      float ev[8] = {ev0.x,ev0.y,ev0.z,ev0.w, ev1.x,ev1.y,ev1.z,ev1.w};
      int   aa[8] = {a00.x,a00.y,a00.z,a00.w, a01.x,a01.y,a01.z,a01.w};
      int   bb[8] = {a10.x,a10.y,a10.z,a10.w, a11.x,a11.y,a11.z,a11.w};
      float wa[8], wb[8];
      #pragma unroll
      for (int j=0;j<8;j++){
        float ya = e1r0 + ev[j];
        ya = fmaxf(ya, 0.25f*ya);
        float ea = exp2f(ya);
        wa[j] = (aa[j] > 0) ? ea : 0.f;
        psum0 += wa[j];
        float yb = e1r1 + ev[j];
        yb = fmaxf(yb, 0.25f*yb);
        float eb = exp2f(yb);
        wb[j] = (bb[j] > 0) ? eb : 0.f;
        psum1 += wb[j];
      }
      union { short8 s; unsigned int u[4]; } pa, pb;
      #pragma unroll
      for (int j=0;j<4;j++){
        pa.u[j] = pk_bf16(wa[2*j], wa[2*j+1]);
        pb.u[j] = pk_bf16(wb[2*j], wb[2*j+1]);
      }
      *(short8*)&Afrag[buf][rt0  ][ksl][l][0] = pa.s;
      *(short8*)&Afrag[buf][rt0+2][ksl][l][0] = pb.s;
    }
    if (c+1 < NCH){
      a00 = __builtin_nontemporal_load(ap0 + (c+1)*32);
      a01 = __builtin_nontemporal_load(ap0 + (c+1)*32 + 1);
      a10 = __builtin_nontemporal_load(ap1 + (c+1)*32);
      a11 = __builtin_nontemporal_load(ap1 + (c+1)*32 + 1);
      ev0 = ep[(c+1)*32];
      ev1 = ep[(c+1)*32 + 1];
    }
    __syncthreads();
    #pragma unroll
    for (int ks=0; ks<4; ks++){
      short8 b8 = *(const short8*)(bcol + c*128 + ks*32);
      #pragma unroll
      for (int rt=0; rt<4; rt++){
        short8 a8 = *(const short8*)&Afrag[buf][rt][ks][l][0];
        acc[rt] = __builtin_amdgcn_mfma_f32_16x16x32_bf16(a8, b8, acc[rt], 0, 0, 0);
      }
    }
    __syncthreads();
  }
  psum0 += __shfl_xor(psum0, 16);
  psum0 += __shfl_xor(psum0, 32);
  psum1 += __shfl_xor(psum1, 16);
  psum1 += __shfl_xor(psum1, 32);
  if (l < 16){
    pden_sh[row0][ksl] = psum0;
    pden_sh[row1][ksl] = psum1;
  }
  __syncthreads();
  const size_t pb = ((size_t)v*KS + ksid)*(N/M2) + blockIdx.x;
  float* pa = pacc + pb*(M2*H);
  #pragma unroll
  for (int rt=0; rt<4; rt++){
    #pragma unroll
    for (int reg=0; reg<4; reg++){
      const int row = rt*16 + quad*4 + reg;
      pa[row*H + col] = acc[rt][reg];
    }
  }
  if (t < M2){
    float den = pden_sh[t][0] + pden_sh[t][1] + pden_sh[t][2] + pden_sh[t][3];
    pdenG[pb*M2 + t] = den;
  }
}

// ---------------- K3: fused combine+epilogue, MFMA QKV, VALU attention, MFMA fc ----------------
// 16 nodes/block, 256 thr (4 waves). QKV/fc GEMMs via MFMA (bf16 fragments built
// in LDS, B from wq4T contiguous-k); only the exp/outer-product attention stays VALU.
__global__ __launch_bounds__(256) void k3_sgfe(
    const float* __restrict__ pacc, const float* __restrict__ pdenG,
    const float* __restrict__ mlp_out,
    const float* __restrict__ gac_b, const float* __restrict__ mlp_b,
    const unsigned short* __restrict__ wq4T,
    const float* __restrict__ qb, const float* __restrict__ kb,
    const float* __restrict__ vb, const float* __restrict__ fcb,
    const float* __restrict__ confw, const float* __restrict__ confb,
    float* __restrict__ feat2)
{
  const int v = blockIdx.y;
  const int n0 = blockIdx.x * 16;
  const int t = threadIdx.x;
  const int w = t >> 6, l = t & 63;
  const int c16 = l & 15, quad = l >> 4;
  __shared__ __align__(16) unsigned short Ffrag[4][64][8];   // feat A-fragments
  __shared__ __align__(16) unsigned short Gfrag[4][64][8];   // agg A-fragments
  __shared__ float Qs[16][H];
  __shared__ float2 KVs[16][H];
  __shared__ float pc[16][4];
  __shared__ float confs[16];

  // ---- fused split-K combine + GAC epilogue -> bf16 F fragments ----
  {
    const int col = t & 127, rh = t >> 7;
    const int bx2 = blockIdx.x >> 2;
    const int lr0 = (blockIdx.x & 3) * 16;
    const float gbv = gac_b[v*H + col];
    const float mbv = mlp_b[v*H + col];
    const int ks = col >> 5, q2 = (col & 31) >> 3, j = col & 7;
    #pragma unroll
    for (int i=0;i<8;i++){
      const int r = rh*8 + i;
      float num = 0.f, den = 0.f;
      #pragma unroll
      for (int s=0;s<KS;s++){
        const size_t pb = ((size_t)v*KS + s)*(N/M2) + bx2;
        num += pacc[pb*(M2*H) + (size_t)(lr0+r)*H + col];
        den += pdenG[pb*M2 + lr0 + r];
      }
      float x = num/den + gbv;
      x = (x >= 0.f) ? x : 0.25f*x;
      x += mlp_out[((size_t)v*N + n0 + r)*H + col] + mbv;
      Ffrag[ks][r + 16*q2][j] = f2bf(x);
    }
  }
  __syncthreads();
  // ---- QKV MFMA: wave w covers col-tiles {2w, 2w+1} for q,k,v ----
  const int colw0 = 2*w*16 + c16;
  {
    const unsigned short* bq = wq4T + (((size_t)0*V + v)*H + colw0)*H + quad*8;
    const unsigned short* bk = wq4T + (((size_t)1*V + v)*H + colw0)*H + quad*8;
    const unsigned short* bv = wq4T + (((size_t)2*V + v)*H + colw0)*H + quad*8;
    floatx4 aq[2], ak[2], av[2];
    #pragma unroll
    for (int c=0;c<2;c++){ aq[c]=(floatx4){0,0,0,0}; ak[c]=(floatx4){0,0,0,0}; av[c]=(floatx4){0,0,0,0}; }
    #pragma unroll
    for (int ks=0; ks<4; ks++){
      short8 a8 = *(const short8*)&Ffrag[ks][l][0];
      #pragma unroll
      for (int c=0;c<2;c++){
        short8 q8 = *(const short8*)(bq + (size_t)c*16*H + ks*32);
        short8 k8 = *(const short8*)(bk + (size_t)c*16*H + ks*32);
        short8 v8 = *(const short8*)(bv + (size_t)c*16*H + ks*32);
        aq[c] = __builtin_amdgcn_mfma_f32_16x16x32_bf16(a8, q8, aq[c], 0,0,0);
        ak[c] = __builtin_amdgcn_mfma_f32_16x16x32_bf16(a8, k8, ak[c], 0,0,0);
        av[c] = __builtin_amdgcn_mfma_f32_16x16x32_bf16(a8, v8, av[c], 0,0,0);
      }
    }
    #pragma unroll
    for (int c=0;c<2;c++){
      const int col = colw0 + c*16;
      const float qbv = qb[v*H+col], kbv = kb[v*H+col], vbv = vb[v*H+col];
      #pragma unroll
      for (int reg=0;reg<4;reg++){
        const int node = quad*4 + reg;
        Qs[node][col] = aq[c][reg] + qbv;
        KVs[node][col] = make_float2(ak[c][reg] + kbv, av[c][reg] + vbv);
      }
    }
  }
  __syncthreads();
  // ---- attention (VALU): wave w -> nodes 4w..4w+3; lane covers dims l, l+64 ----
  const float invs = 0.08838834764831845f;  // 1/sqrt(128)
  #pragma unroll
  for (int p=0;p<4;p++){
    const int r = 4*w + p;
    const float qa  = Qs[r][l]    * invs;
    const float qb2 = Qs[r][l+64] * invs;
    float sA=0.f, aA=0.f, sB=0.f, aB=0.f;
    const float4* kvp = (const float4*)&KVs[r][0];
    #pragma unroll 4
    for (int oo=0; oo<H/2; oo++){
      float4 kv2 = kvp[oo];
      float eA0 = __expf(qa*kv2.x);  sA += eA0; aA = fmaf(eA0, kv2.y, aA);
      float eA1 = __expf(qa*kv2.z);  sA += eA1; aA = fmaf(eA1, kv2.w, aA);
      float eB0 = __expf(qb2*kv2.x); sB += eB0; aB = fmaf(eB0, kv2.y, aB);
      float eB1 = __expf(qb2*kv2.z); sB += eB1; aB = fmaf(eB1, kv2.w, aB);
    }
    // write agg into fc A-fragments (dims l and l+64)
    Gfrag[l>>5][r + 16*((l&31)>>3)][l&7] = f2bf(aA/sA);
    Gfrag[2 + (l>>5)][r + 16*((l&31)>>3)][l&7] = f2bf(aB/sB);
  }
  __syncthreads();
  // ---- fc MFMA + relu + conf gate ----
  const unsigned short* bf = wq4T + (((size_t)3*V + v)*H + colw0)*H + quad*8;
  floatx4 af[2];
  af[0]=(floatx4){0,0,0,0}; af[1]=(floatx4){0,0,0,0};
  #pragma unroll
  for (int ks=0; ks<4; ks++){
    short8 a8 = *(const short8*)&Gfrag[ks][l][0];
    #pragma unroll
    for (int c=0;c<2;c++){
      short8 b8 = *(const short8*)(bf + (size_t)c*16*H + ks*32);
      af[c] = __builtin_amdgcn_mfma_f32_16x16x32_bf16(a8, b8, af[c], 0,0,0);
    }
  }
  float g[2][4];
  float pn[4] = {0.f,0.f,0.f,0.f};
  #pragma unroll
  for (int c=0;c<2;c++){
    const int col = colw0 + c*16;
    const float fcbv = fcb[v*H+col];
    const float cwv  = confw[v*H+col];
    #pragma unroll
    for (int reg=0;reg<4;reg++){
      float gg = fmaxf(af[c][reg] + fcbv, 0.f);
      g[c][reg] = gg;
      pn[reg] += gg*cwv;
    }
  }
  #pragma unroll
  for (int reg=0;reg<4;reg++){
    pn[reg] += __shfl_xor(pn[reg], 1);
    pn[reg] += __shfl_xor(pn[reg], 2);
    pn[reg] += __shfl_xor(pn[reg], 4);
    pn[reg] += __shfl_xor(pn[reg], 8);
  }
  if (c16 == 0){
    #pragma unroll
    for (int reg=0;reg<4;reg++) pc[quad*4 + reg][w] = pn[reg];
  }
  __syncthreads();
  if (t < 16) confs[t] = pc[t][0] + pc[t][1] + pc[t][2] + pc[t][3] + confb[v];
  __syncthreads();
  #pragma unroll
  for (int c=0;c<2;c++){
    const int col = colw0 + c*16;
    #pragma unroll
    for (int reg=0;reg<4;reg++){
      const int node = quad*4 + reg;
      feat2[((size_t)v*N + n0 + node)*H + col] = g[c][reg]*confs[node];
    }
  }
}

// ---------------- K4: final classifier [N, V*H] @ [V*H, C] ----------------
__global__ __launch_bounds__(64) void k4_cls(
    const float* __restrict__ feat2,
    const float* __restrict__ mm_w, const float* __restrict__ mm_b,
    float* __restrict__ out)
{
  const int n = blockIdx.x, t = threadIdx.x;
  float a[C] = {0,0,0,0,0};
  for (int j=t; j<V*H; j+=64){
    int vv = j >> 7, hh = j & (H-1);
    float f = feat2[((size_t)vv*N + n)*H + hh];
    #pragma unroll
    for (int c=0;c<C;c++) a[c] = fmaf(f, mm_w[j*C+c], a[c]);
  }
  #pragma unroll
  for (int c=0;c<C;c++){
    #pragma unroll
    for (int o=32;o>0;o>>=1) a[c] += __shfl_down(a[c],o);
  }
  if (t==0){
    #pragma unroll
    for (int c=0;c<C;c++) out[(size_t)n*C+c] = a[c] + mm_b[c];
  }
}

extern "C" void kernel_launch(void* const* d_in, const int* in_sizes, int n_in,
                              void* d_out, int out_size, void* d_ws, size_t ws_size,
                              hipStream_t stream)
{
  (void)in_sizes; (void)n_in; (void)out_size; (void)ws_size;
  const float* data  = (const float*)d_in[0];
  const int*   adj   = (const int*)d_in[1];
  const float* gac_w = (const float*)d_in[2];
  const float* gac_b = (const float*)d_in[3];
  const float* a1    = (const float*)d_in[4];
  const float* a2    = (const float*)d_in[5];
  const float* mlp_w = (const float*)d_in[6];
  const float* mlp_b = (const float*)d_in[7];
  const float* q_w   = (const float*)d_in[8];
  const float* q_b   = (const float*)d_in[9];
  const float* k_w   = (const float*)d_in[10];
  const float* k_b   = (const float*)d_in[11];
  const float* v_w   = (const float*)d_in[12];
  const float* v_b   = (const float*)d_in[13];
  const float* fc_w  = (const float*)d_in[14];
  const float* fc_b  = (const float*)d_in[15];
  const float* cw    = (const float*)d_in[16];
  const float* cb    = (const float*)d_in[17];
  const float* mm_w  = (const float*)d_in[18];
  const float* mm_b  = (const float*)d_in[19];

  float* ws = (float*)d_ws;
  const size_t VNH = (size_t)V*N*H;
  float* mlp   = ws;
  float* feat2 = ws + VNH;
  float* e1    = ws + 2*VNH;
  float* e2    = e1 + (size_t)V*N;
  unsigned short* hT   = (unsigned short*)(e2 + (size_t)V*N); // [V][H][N] bf16
  unsigned short* wT   = hT + VNH;                            // [2][V][H][D] bf16
  unsigned short* wq4T = wT + (size_t)2*V*H*D;                // [4][V][H][H] bf16
  float* pacc  = (float*)(wq4T + (size_t)4*V*H*H);            // [V][KS][N/M2][M2][H]
  float* pden  = pacc + (size_t)V*KS*(N/M2)*M2*H;             // [V][KS][N/M2][M2]

  k0_wt  <<<dim3(V, 2, D/64), 256, 0, stream>>>(gac_w, mlp_w, wT);
  k0b_wt <<<dim3(V, 4, H/64), 256, 0, stream>>>(q_w, k_w, v_w, fc_w, wq4T);
  k1_gemm<<<dim3(N/M1, V),    512, 0, stream>>>(data, wT, a1, a2, hT, mlp, e1, e2);
  k2_attn<<<dim3(N/M2, KS, V),512, 0, stream>>>(hT, adj, e1, e2, pacc, pden);
  k3_sgfe<<<dim3(N/16, V),    256, 0, stream>>>(pacc, pden, mlp, gac_b, mlp_b,
                                                wq4T, q_b, k_b, v_b, fc_b,
                                                cw, cb, feat2);
  k4_cls <<<dim3(N),           64, 0, stream>>>(feat2, mm_w, mm_b, (float*)d_out);
}